// Round 3
// baseline (131.718 us; speedup 1.0000x reference)
//
#include <hip/hip_runtime.h>
#include <hip/hip_bf16.h>

#define S 1024
#define C 384
#define NC 32
#define SHIFT 0.3f
#define NTILE 528            // 32*33/2 triangular tiles of 32x32 per batch
#define NBLK (NTILE * 4)     // 2112 blocks total

typedef __attribute__((ext_vector_type(4))) float f32x4;
typedef __attribute__((ext_vector_type(8))) short short8;

// f32 -> bf16 (round-to-nearest-even), raw-bit version (finite inputs only)
__device__ __forceinline__ unsigned int f2bf(float x) {
  unsigned int u = __builtin_bit_cast(unsigned int, x);
  unsigned int rb = ((u >> 16) & 1u) + 0x7fffu;
  return (u + rb) >> 16;
}
__device__ __forceinline__ unsigned int f2bf2(float lo, float hi) {
  return f2bf(lo) | (f2bf(hi) << 16);
}

// async global->LDS, 16B per lane; LDS dest is wave-uniform base + lane*16
__device__ __forceinline__ void gld16(void* lds, const void* g) {
  __builtin_amdgcn_global_load_lds(
      (const __attribute__((address_space(1))) void*)g,
      (__attribute__((address_space(3))) void*)lds, 16, 0, 0);
}

// ---- prep: normalize f -> bf16 fnb; exp(p)/p -> bf16 Eb/Pb; rowdot ----
__global__ __launch_bounds__(256) void k_prep(const float* __restrict__ f,
                                              const float* __restrict__ p,
                                              unsigned int* __restrict__ fnb,
                                              unsigned int* __restrict__ Eb,
                                              unsigned int* __restrict__ Pb,
                                              float* __restrict__ rowdot,
                                              float* __restrict__ accum) {
  // zero global accumulators: 8 replicas x 8 floats + counter (+pad) each replay
  if (blockIdx.x == 0 && threadIdx.x < 72) accum[threadIdx.x] = 0.f;

  if (blockIdx.x < 1024) {
    int lane = threadIdx.x & 63;
    int row = blockIdx.x * 4 + (threadIdx.x >> 6);
    const float* fr = f + (size_t)row * C;
    float2 v[3];
    float ss = 0.f;
#pragma unroll
    for (int j = 0; j < 3; ++j) {
      v[j] = *(const float2*)(fr + 2 * lane + 128 * j);
      ss = fmaf(v[j].x, v[j].x, fmaf(v[j].y, v[j].y, ss));
    }
#pragma unroll
    for (int m = 32; m >= 1; m >>= 1) ss += __shfl_xor(ss, m, 64);
    float s = 1.f / fmaxf(sqrtf(ss), 1e-12f);
    unsigned int* outr = fnb + (size_t)row * (C / 2);
#pragma unroll
    for (int j = 0; j < 3; ++j) outr[lane + 64 * j] = f2bf2(v[j].x * s, v[j].y * s);
  } else {
    int t = (blockIdx.x - 1024) * 256 + threadIdx.x;  // [0, 16384)
    int r = t >> 2, q = t & 3;
    const float* pr = p + (size_t)r * NC + q * 8;
    float4 a = *(const float4*)pr;
    float4 b = *(const float4*)(pr + 4);
    float ea0 = __expf(a.x), ea1 = __expf(a.y), ea2 = __expf(a.z), ea3 = __expf(a.w);
    float eb0 = __expf(b.x), eb1 = __expf(b.y), eb2 = __expf(b.z), eb3 = __expf(b.w);
    uint4 ue = make_uint4(f2bf2(ea0, ea1), f2bf2(ea2, ea3), f2bf2(eb0, eb1), f2bf2(eb2, eb3));
    uint4 up = make_uint4(f2bf2(a.x, a.y), f2bf2(a.z, a.w), f2bf2(b.x, b.y), f2bf2(b.z, b.w));
    *(uint4*)(Eb + r * 16 + q * 4) = ue;
    *(uint4*)(Pb + r * 16 + q * 4) = up;
    float s = ea0 * a.x + ea1 * a.y + ea2 * a.z + ea3 * a.w +
              eb0 * b.x + eb1 * b.y + eb2 * b.z + eb3 * b.w;
    s += __shfl_xor(s, 1, 64);
    s += __shfl_xor(s, 2, 64);
    if (q == 0) rowdot[r] = s;
  }
}

// ---- pairwise, TRIANGULAR 32x32 tiles, FULL K=384 staged in one shot ----
// Per wave: 12 back-to-back gld16 (12KB in flight), ONE __syncthreads (drains
// vmcnt), then 12 MFMAs. No K-loop, no software pipeline, no per-iter barriers.
// 2112 blocks (528 tri-tiles x 4 batches), XCD-swizzled so each XCD works on
// half of one batch's tiles (~1MB working set -> L2-resident after warmup).
// LDS layout seg-major: As[seg][row][128B], chunk-XOR swizzle as before.
__global__ __launch_bounds__(256, 2) void k_pair(
    const unsigned short* __restrict__ fnb, const unsigned short* __restrict__ Eb,
    const unsigned short* __restrict__ Pb, const float* __restrict__ rowdot,
    float* __restrict__ accum, float* __restrict__ out) {
  __shared__ unsigned short As[6 * 32 * 64];  // 6 segs x 32 rows x 128B = 24KB
  __shared__ unsigned short Bs[6 * 32 * 64];
  __shared__ float4 red[4];

  const int tid = threadIdx.x;
  const int lane = tid & 63;
  const int wave = tid >> 6;
  const int lan = lane & 15, quad = lane >> 4;
  const int wr = wave >> 1, wc = wave & 1;  // wave's 16x16 quadrant of 32x32 tile

  // XCD-aware bijective swizzle: 2112 % 8 == 0, chunk 264 per XCD.
  const int orig = blockIdx.x;
  const int wk = (orig >> 3) + (orig & 7) * (NBLK / 8);
  const int n = wk / NTILE;
  int rem = wk - n * NTILE, ty = 0;
  while (rem >= 32 - ty) {
    rem -= 32 - ty;
    ++ty;
  }
  const int tx = ty + rem;
  const int sBase = ty * 32;
  const int lBase = tx * 32;

  // stage FULL K: each wave stages 8 rows (r8) of A and B; 6 segs of 128B each.
  const int r8 = lane >> 3, c8 = lane & 7;
  const char* gA = (const char*)fnb +
                   ((size_t)(n * S + sBase + 8 * wave + r8)) * 768 + ((c8 ^ r8) << 4);
  const char* gB = (const char*)fnb +
                   ((size_t)(n * S + lBase + 8 * wave + r8)) * 768 + ((c8 ^ r8) << 4);
  char* lA = (char*)As + (8 * wave) * 128;
  char* lB = (char*)Bs + (8 * wave) * 128;
#pragma unroll
  for (int seg = 0; seg < 6; ++seg) {
    gld16(lA + seg * 4096, gA + seg * 128);
    gld16(lB + seg * 4096, gB + seg * 128);
  }
  __syncthreads();  // drains vmcnt(0): all 24KB+24KB staged

  // compute: 12 MFMAs over K=384, single 16x16 output per wave
  const int rowA = wr * 16 + lan;
  const int rowB = wc * 16 + lan;
  f32x4 acc = (f32x4){0.f, 0.f, 0.f, 0.f};
#pragma unroll
  for (int kk = 0; kk < 12; ++kk) {
    const int seg = kk >> 1, ks = kk & 1;
    short8 af = *(const short8*)((const char*)As + seg * 4096 + rowA * 128 +
                                 ((((ks << 2) | quad) ^ (rowA & 7)) << 4));
    short8 bf = *(const short8*)((const char*)Bs + seg * 4096 + rowB * 128 +
                                 ((((ks << 2) | quad) ^ (rowB & 7)) << 4));
    acc = __builtin_amdgcn_mfma_f32_16x16x32_bf16(af, bf, acc, 0, 0, 0);
  }

  // epilogue: dual EP mini-GEMMs + weighted triangular reduction
  // C/D layout: row(m=s) = quad*4+reg, col(n=l) = lan
  const size_t sRow = (size_t)(n * S + sBase + wr * 16 + lan) * 32 + quad * 8;
  short8 eas = *(const short8*)(Eb + sRow);
  short8 ps = *(const short8*)(Pb + sRow);
  const size_t lRow = (size_t)(n * S + lBase + wc * 16 + lan) * 32 + quad * 8;
  short8 pl = *(const short8*)(Pb + lRow);
  short8 eal = *(const short8*)(Eb + lRow);
  f32x4 z = (f32x4){0.f, 0.f, 0.f, 0.f};
  f32x4 ep1 = __builtin_amdgcn_mfma_f32_16x16x32_bf16(eas, pl, z, 0, 0, 0);
  f32x4 ep2 = __builtin_amdgcn_mfma_f32_16x16x32_bf16(ps, eal, z, 0, 0, 0);

  float rd_s[4];
  {
    int gs0 = n * S + sBase + wr * 16 + quad * 4;
#pragma unroll
    for (int r = 0; r < 4; ++r) rd_s[r] = rowdot[gs0 + r];
  }
  const int gl = lBase + wc * 16 + lan;
  const float rd_l = rowdot[n * S + gl];

  float pos_s = 0.f, neg_s = 0.f, posc = 0.f, negc = 0.f;
#pragma unroll
  for (int r = 0; r < 4; ++r) {
    int gs = sBase + wr * 16 + quad * 4 + r;
    float w1 = (gl >= gs) ? 1.f : 0.f;
    float w2 = (gl > gs) ? 1.f : 0.f;
    float fc = acc[r] - SHIFT;
    float contrib = w1 * (rd_s[r] - ep1[r]) + w2 * (rd_l - ep2[r]);
    float cnt = w1 + w2;
    if (fc > 0.f) {
      pos_s = fmaf(fc, contrib, pos_s);
      posc += cnt;
    } else if (fc < 0.f) {
      neg_s = fmaf(fc, contrib, neg_s);
      negc += cnt;
    }
  }
#pragma unroll
  for (int m = 32; m >= 1; m >>= 1) {
    pos_s += __shfl_xor(pos_s, m, 64);
    neg_s += __shfl_xor(neg_s, m, 64);
    posc += __shfl_xor(posc, m, 64);
    negc += __shfl_xor(negc, m, 64);
  }
  if (lane == 0) red[wave] = make_float4(pos_s, neg_s, posc, negc);
  __syncthreads();
  if (tid == 0) {
    float4 t = red[0];
#pragma unroll
    for (int w = 1; w < 4; ++w) {
      t.x += red[w].x;
      t.y += red[w].y;
      t.z += red[w].z;
      t.w += red[w].w;
    }
    // 8 accumulator replicas (one per XCD) to spread same-line atomic contention
    float* ar = accum + (orig & 7) * 8;
    atomicAdd(&ar[0], t.x);
    atomicAdd(&ar[1], t.y);
    atomicAdd(&ar[2], t.z);
    atomicAdd(&ar[3], t.w);
    __threadfence();
    unsigned int old = atomicAdd((unsigned int*)(accum + 64), 1u);
    if (old == NBLK - 1) {
      __threadfence();
      float px = 0.f, ng = 0.f, pc = 0.f, nc = 0.f;
#pragma unroll
      for (int rep = 0; rep < 8; ++rep) {
        px += atomicAdd(&accum[rep * 8 + 0], 0.f);
        ng += atomicAdd(&accum[rep * 8 + 1], 0.f);
        pc += atomicAdd(&accum[rep * 8 + 2], 0.f);
        nc += atomicAdd(&accum[rep * 8 + 3], 0.f);
      }
      out[0] = px / pc;
      out[1] = ng / nc;
    }
  }
}

extern "C" void kernel_launch(void* const* d_in, const int* in_sizes, int n_in,
                              void* d_out, int out_size, void* d_ws, size_t ws_size,
                              hipStream_t stream) {
  const float* f = (const float*)d_in[0];  // feats [4,32,32,384] f32
  const float* p = (const float*)d_in[1];  // p_class [4,32,32,32] f32 (log-probs)
  float* out = (float*)d_out;              // [pos, neg]
  float* ws = (float*)d_ws;
  // ws layout (floats): rowdot @0 (4096) | accum @4096 (72: 8 replicas + counter) |
  // fnb @16384 (786432) | Eb @802816 (65536) | Pb @868352 (65536)
  float* rowdot = ws;
  float* accum = ws + 4096;
  unsigned int* fnb = (unsigned int*)(ws + 16384);
  unsigned int* Eb = (unsigned int*)(ws + 802816);
  unsigned int* Pb = (unsigned int*)(ws + 868352);

  k_prep<<<dim3(1088), dim3(256), 0, stream>>>(f, p, fnb, Eb, Pb, rowdot, accum);
  k_pair<<<dim3(NBLK), dim3(256), 0, stream>>>((const unsigned short*)fnb,
                                               (const unsigned short*)Eb,
                                               (const unsigned short*)Pb, rowdot,
                                               accum, out);
}

// Round 10
// 72.049 us; speedup vs baseline: 1.8282x; 1.8282x over previous
//
#include <hip/hip_runtime.h>
#include <hip/hip_bf16.h>

#define S 1024
#define C 384
#define NC 32
#define SHIFT 0.3f
#define NTILE 528            // 32*33/2 triangular tiles of 32x32 per batch
#define NBLK (NTILE * 4)     // 2112 blocks total

typedef __attribute__((ext_vector_type(4))) float f32x4;
typedef __attribute__((ext_vector_type(8))) short short8;

// f32 -> bf16 (round-to-nearest-even), raw-bit version (finite inputs only)
__device__ __forceinline__ unsigned int f2bf(float x) {
  unsigned int u = __builtin_bit_cast(unsigned int, x);
  unsigned int rb = ((u >> 16) & 1u) + 0x7fffu;
  return (u + rb) >> 16;
}
__device__ __forceinline__ unsigned int f2bf2(float lo, float hi) {
  return f2bf(lo) | (f2bf(hi) << 16);
}

// async global->LDS, 16B per lane; LDS dest is wave-uniform base + lane*16
__device__ __forceinline__ void gld16(void* lds, const void* g) {
  __builtin_amdgcn_global_load_lds(
      (const __attribute__((address_space(1))) void*)g,
      (__attribute__((address_space(3))) void*)lds, 16, 0, 0);
}

// ---- prep: normalize f -> bf16 fnb; exp(p)/p -> bf16 Eb/Pb; rowdot ----
__global__ __launch_bounds__(256) void k_prep(const float* __restrict__ f,
                                              const float* __restrict__ p,
                                              unsigned int* __restrict__ fnb,
                                              unsigned int* __restrict__ Eb,
                                              unsigned int* __restrict__ Pb,
                                              float* __restrict__ rowdot) {
  if (blockIdx.x < 1024) {
    int lane = threadIdx.x & 63;
    int row = blockIdx.x * 4 + (threadIdx.x >> 6);
    const float* fr = f + (size_t)row * C;
    float2 v[3];
    float ss = 0.f;
#pragma unroll
    for (int j = 0; j < 3; ++j) {
      v[j] = *(const float2*)(fr + 2 * lane + 128 * j);
      ss = fmaf(v[j].x, v[j].x, fmaf(v[j].y, v[j].y, ss));
    }
#pragma unroll
    for (int m = 32; m >= 1; m >>= 1) ss += __shfl_xor(ss, m, 64);
    float s = 1.f / fmaxf(sqrtf(ss), 1e-12f);
    unsigned int* outr = fnb + (size_t)row * (C / 2);
#pragma unroll
    for (int j = 0; j < 3; ++j) outr[lane + 64 * j] = f2bf2(v[j].x * s, v[j].y * s);
  } else {
    int t = (blockIdx.x - 1024) * 256 + threadIdx.x;  // [0, 16384)
    int r = t >> 2, q = t & 3;
    const float* pr = p + (size_t)r * NC + q * 8;
    float4 a = *(const float4*)pr;
    float4 b = *(const float4*)(pr + 4);
    float ea0 = __expf(a.x), ea1 = __expf(a.y), ea2 = __expf(a.z), ea3 = __expf(a.w);
    float eb0 = __expf(b.x), eb1 = __expf(b.y), eb2 = __expf(b.z), eb3 = __expf(b.w);
    uint4 ue = make_uint4(f2bf2(ea0, ea1), f2bf2(ea2, ea3), f2bf2(eb0, eb1), f2bf2(eb2, eb3));
    uint4 up = make_uint4(f2bf2(a.x, a.y), f2bf2(a.z, a.w), f2bf2(b.x, b.y), f2bf2(b.z, b.w));
    *(uint4*)(Eb + r * 16 + q * 4) = ue;
    *(uint4*)(Pb + r * 16 + q * 4) = up;
    float s = ea0 * a.x + ea1 * a.y + ea2 * a.z + ea3 * a.w +
              eb0 * b.x + eb1 * b.y + eb2 * b.z + eb3 * b.w;
    s += __shfl_xor(s, 1, 64);
    s += __shfl_xor(s, 2, 64);
    if (q == 0) rowdot[r] = s;
  }
}

// ---- pairwise, TRIANGULAR 32x32 tiles, FULL K=384 staged in one shot ----
// Per wave: 12 back-to-back gld16 (12KB in flight), ONE __syncthreads (drains
// vmcnt), then 12 MFMAs. 2112 blocks, XCD-swizzled for L2 locality.
// NO global atomics: each block writes ONE float4 partial (plain store);
// k_final reduces. (Round-3 lesson: same-line atomic serialization at ~17ns/op
// dominated k_pair — 2720 ops ~ 47us, 10560 ops ~ 88us.)
__global__ __launch_bounds__(256, 2) void k_pair(
    const unsigned short* __restrict__ fnb, const unsigned short* __restrict__ Eb,
    const unsigned short* __restrict__ Pb, const float* __restrict__ rowdot,
    float* __restrict__ partials) {
  __shared__ unsigned short As[6 * 32 * 64];  // 6 segs x 32 rows x 128B = 24KB
  __shared__ unsigned short Bs[6 * 32 * 64];
  __shared__ float4 red[4];

  const int tid = threadIdx.x;
  const int lane = tid & 63;
  const int wave = tid >> 6;
  const int lan = lane & 15, quad = lane >> 4;
  const int wr = wave >> 1, wc = wave & 1;  // wave's 16x16 quadrant of 32x32 tile

  // XCD-aware bijective swizzle: 2112 % 8 == 0, chunk 264 per XCD.
  const int orig = blockIdx.x;
  const int wk = (orig >> 3) + (orig & 7) * (NBLK / 8);
  const int n = wk / NTILE;
  int rem = wk - n * NTILE, ty = 0;
  while (rem >= 32 - ty) {
    rem -= 32 - ty;
    ++ty;
  }
  const int tx = ty + rem;
  const int sBase = ty * 32;
  const int lBase = tx * 32;

  // stage FULL K: each wave stages 8 rows (r8) of A and B; 6 segs of 128B each.
  const int r8 = lane >> 3, c8 = lane & 7;
  const char* gA = (const char*)fnb +
                   ((size_t)(n * S + sBase + 8 * wave + r8)) * 768 + ((c8 ^ r8) << 4);
  const char* gB = (const char*)fnb +
                   ((size_t)(n * S + lBase + 8 * wave + r8)) * 768 + ((c8 ^ r8) << 4);
  char* lA = (char*)As + (8 * wave) * 128;
  char* lB = (char*)Bs + (8 * wave) * 128;
#pragma unroll
  for (int seg = 0; seg < 6; ++seg) {
    gld16(lA + seg * 4096, gA + seg * 128);
    gld16(lB + seg * 4096, gB + seg * 128);
  }
  __syncthreads();  // drains vmcnt(0): all 24KB+24KB staged

  // compute: 12 MFMAs over K=384, single 16x16 output per wave
  const int rowA = wr * 16 + lan;
  const int rowB = wc * 16 + lan;
  f32x4 acc = (f32x4){0.f, 0.f, 0.f, 0.f};
#pragma unroll
  for (int kk = 0; kk < 12; ++kk) {
    const int seg = kk >> 1, ks = kk & 1;
    short8 af = *(const short8*)((const char*)As + seg * 4096 + rowA * 128 +
                                 ((((ks << 2) | quad) ^ (rowA & 7)) << 4));
    short8 bf = *(const short8*)((const char*)Bs + seg * 4096 + rowB * 128 +
                                 ((((ks << 2) | quad) ^ (rowB & 7)) << 4));
    acc = __builtin_amdgcn_mfma_f32_16x16x32_bf16(af, bf, acc, 0, 0, 0);
  }

  // epilogue: dual EP mini-GEMMs + weighted triangular reduction
  // C/D layout: row(m=s) = quad*4+reg, col(n=l) = lan
  const size_t sRow = (size_t)(n * S + sBase + wr * 16 + lan) * 32 + quad * 8;
  short8 eas = *(const short8*)(Eb + sRow);
  short8 ps = *(const short8*)(Pb + sRow);
  const size_t lRow = (size_t)(n * S + lBase + wc * 16 + lan) * 32 + quad * 8;
  short8 pl = *(const short8*)(Pb + lRow);
  short8 eal = *(const short8*)(Eb + lRow);
  f32x4 z = (f32x4){0.f, 0.f, 0.f, 0.f};
  f32x4 ep1 = __builtin_amdgcn_mfma_f32_16x16x32_bf16(eas, pl, z, 0, 0, 0);
  f32x4 ep2 = __builtin_amdgcn_mfma_f32_16x16x32_bf16(ps, eal, z, 0, 0, 0);

  float rd_s[4];
  {
    int gs0 = n * S + sBase + wr * 16 + quad * 4;
#pragma unroll
    for (int r = 0; r < 4; ++r) rd_s[r] = rowdot[gs0 + r];
  }
  const int gl = lBase + wc * 16 + lan;
  const float rd_l = rowdot[n * S + gl];

  float pos_s = 0.f, neg_s = 0.f, posc = 0.f, negc = 0.f;
#pragma unroll
  for (int r = 0; r < 4; ++r) {
    int gs = sBase + wr * 16 + quad * 4 + r;
    float w1 = (gl >= gs) ? 1.f : 0.f;
    float w2 = (gl > gs) ? 1.f : 0.f;
    float fc = acc[r] - SHIFT;
    float contrib = w1 * (rd_s[r] - ep1[r]) + w2 * (rd_l - ep2[r]);
    float cnt = w1 + w2;
    if (fc > 0.f) {
      pos_s = fmaf(fc, contrib, pos_s);
      posc += cnt;
    } else if (fc < 0.f) {
      neg_s = fmaf(fc, contrib, neg_s);
      negc += cnt;
    }
  }
#pragma unroll
  for (int m = 32; m >= 1; m >>= 1) {
    pos_s += __shfl_xor(pos_s, m, 64);
    neg_s += __shfl_xor(neg_s, m, 64);
    posc += __shfl_xor(posc, m, 64);
    negc += __shfl_xor(negc, m, 64);
  }
  if (lane == 0) red[wave] = make_float4(pos_s, neg_s, posc, negc);
  __syncthreads();
  if (tid == 0) {
    float4 t = red[0];
#pragma unroll
    for (int w = 1; w < 4; ++w) {
      t.x += red[w].x;
      t.y += red[w].y;
      t.z += red[w].z;
      t.w += red[w].w;
    }
    *(float4*)(&partials[orig * 4]) = t;  // plain coalesced store, no atomics
  }
}

__global__ __launch_bounds__(256) void k_final(const float* __restrict__ partials,
                                               float* __restrict__ out) {
  int tid = threadIdx.x;
  float4 s = make_float4(0.f, 0.f, 0.f, 0.f);
#pragma unroll
  for (int i = 0; i < 9; ++i) {
    int idx = tid + i * 256;
    if (idx < NBLK) {
      float4 v = ((const float4*)partials)[idx];
      s.x += v.x;
      s.y += v.y;
      s.z += v.z;
      s.w += v.w;
    }
  }
#pragma unroll
  for (int m = 32; m >= 1; m >>= 1) {
    s.x += __shfl_xor(s.x, m, 64);
    s.y += __shfl_xor(s.y, m, 64);
    s.z += __shfl_xor(s.z, m, 64);
    s.w += __shfl_xor(s.w, m, 64);
  }
  __shared__ float4 red[4];
  if ((tid & 63) == 0) red[tid >> 6] = s;
  __syncthreads();
  if (tid == 0) {
    float4 t = red[0];
#pragma unroll
    for (int w = 1; w < 4; ++w) {
      t.x += red[w].x;
      t.y += red[w].y;
      t.z += red[w].z;
      t.w += red[w].w;
    }
    out[0] = t.x / t.z;
    out[1] = t.y / t.w;
  }
}

extern "C" void kernel_launch(void* const* d_in, const int* in_sizes, int n_in,
                              void* d_out, int out_size, void* d_ws, size_t ws_size,
                              hipStream_t stream) {
  const float* f = (const float*)d_in[0];  // feats [4,32,32,384] f32
  const float* p = (const float*)d_in[1];  // p_class [4,32,32,32] f32 (log-probs)
  float* out = (float*)d_out;              // [pos, neg]
  float* ws = (float*)d_ws;
  // ws layout (floats): rowdot @0 (4096) | partials @4096 (2112*4=8448) |
  // fnb @16384 (786432) | Eb @802816 (65536) | Pb @868352 (65536)
  float* rowdot = ws;
  float* partials = ws + 4096;
  unsigned int* fnb = (unsigned int*)(ws + 16384);
  unsigned int* Eb = (unsigned int*)(ws + 802816);
  unsigned int* Pb = (unsigned int*)(ws + 868352);

  k_prep<<<dim3(1088), dim3(256), 0, stream>>>(f, p, fnb, Eb, Pb, rowdot);
  k_pair<<<dim3(NBLK), dim3(256), 0, stream>>>((const unsigned short*)fnb,
                                               (const unsigned short*)Eb,
                                               (const unsigned short*)Pb, rowdot,
                                               partials);
  k_final<<<dim3(1), dim3(256), 0, stream>>>(partials, out);
}